// Round 1
// 381.586 us; speedup vs baseline: 1.1298x; 1.1298x over previous
//
#include <hip/hip_runtime.h>
#include <hip/hip_bf16.h>

#define Nn 16384
#define Ff 39
#define Vv 100000
#define Ee 16
#define Dd 624      // F*E
#define KP1 640     // deep width padded to multiple of 64 (zero pad cols 624..639)
#define KP2 448     // x1 width padded to multiple of 64  (zero pad cols 400..447)
#define Hh 400
#define EPSf 1e-5f

typedef short short8 __attribute__((ext_vector_type(8)));
typedef float floatx4 __attribute__((ext_vector_type(4)));

__device__ __forceinline__ unsigned short f2bu(float x) {
  __hip_bfloat16 h = __float2bfloat16(x);
  return *reinterpret_cast<unsigned short*>(&h);
}
__device__ __forceinline__ float bf2f(unsigned short v) {
  union { unsigned int u; float f; } x; x.u = ((unsigned int)v) << 16; return x.f;
}

// async global->LDS, 16B per lane. LDS dst must be wave-uniform base + lane*16.
__device__ __forceinline__ void gload16(void* lds, const void* g) {
  __builtin_amdgcn_global_load_lds(
      (const __attribute__((address_space(1))) unsigned int*)g,
      (__attribute__((address_space(3))) unsigned int*)lds, 16, 0, 0);
}

// ---------------- Kernel 1: embedding gather + FM  |  W1 transpose->bf16 (pad to 640) | zero stats ----------------
// blocks [0,4096): embed rows (1 wave/row, 4 rows/block), float4 gathers
// blocks [4096,4496): W1t[n][k] = bf16(W1[k][n]), k<624, zero pad k 624..639
// block 4496: zero the 4*400 stat accumulators
__global__ __launch_bounds__(256) void embed_kernel(
    const int* __restrict__ xi, const float* __restrict__ xv,
    const float* __restrict__ emb1, const float* __restrict__ emb2,
    const float* __restrict__ bias, const float* __restrict__ W1,
    __hip_bfloat16* __restrict__ deep, float* __restrict__ p,
    __hip_bfloat16* __restrict__ W1t, float* __restrict__ stats,
    __hip_bfloat16* __restrict__ x1b) {
  const int b = blockIdx.x;
  if (b >= 4096) {
    if (b == 4496) {
      for (int i = threadIdx.x; i < 1600; i += 256) stats[i] = 0.f;
    } else {
      const int n = b - 4096;
      for (int k = threadIdx.x; k < KP1; k += 256)
        W1t[(size_t)n * KP1 + k] =
            (k < Dd) ? __float2bfloat16(W1[(size_t)k * Hh + n]) : __float2bfloat16(0.f);
    }
    return;
  }
  __shared__ int   sidx[4][40];
  __shared__ float sxv[4][40];
  const int w = threadIdx.x >> 6;
  const int lane = threadIdx.x & 63;
  const int n = b * 4 + w;
  if (lane < Ff) {
    sidx[w][lane] = xi[n * Ff + lane];
    sxv[w][lane]  = xv[n * Ff + lane];
  }
  __syncthreads();

  // 156 float4 chunks per row; lane handles j4 = lane, lane+64, lane+128.
  // element e = (j4&3)*4 + c -> per-lane e-quad is constant = (lane&3)*4..+3
  const float4* e2v = (const float4*)emb2;
  float se0 = 0.f, se1 = 0.f, se2 = 0.f, se3 = 0.f;
  float qe0 = 0.f, qe1 = 0.f, qe2 = 0.f, qe3 = 0.f;
  #pragma unroll
  for (int t = 0; t < 3; ++t) {
    const int j4 = lane + t * 64;
    if (j4 < 156) {
      const int f = j4 >> 2;
      float4 v = e2v[((long)f * (Vv + 1) + sidx[w][f]) * 4 + (j4 & 3)];
      const float xf = sxv[w][f];
      v.x *= xf; v.y *= xf; v.z *= xf; v.w *= xf;
      *(ushort4*)&deep[(size_t)n * KP1 + j4 * 4] =
          make_ushort4(f2bu(v.x), f2bu(v.y), f2bu(v.z), f2bu(v.w));
      se0 += v.x; qe0 += v.x * v.x;
      se1 += v.y; qe1 += v.y * v.y;
      se2 += v.z; qe2 += v.z * v.z;
      se3 += v.w; qe3 += v.w * v.w;
    }
  }
  // zero pads: deep cols [624,640), x1b cols [400,448)
  if (lane < 4)  *(ushort4*)&deep[(size_t)n * KP1 + Dd + lane * 4] = make_ushort4(0, 0, 0, 0);
  if (lane < 12) *(ushort4*)&x1b [(size_t)n * KP2 + Hh + lane * 4] = make_ushort4(0, 0, 0, 0);

  // sum over f: combine lanes with equal (lane&3)
  #pragma unroll
  for (int d = 4; d < 64; d <<= 1) {
    se0 += __shfl_xor(se0, d); qe0 += __shfl_xor(qe0, d);
    se1 += __shfl_xor(se1, d); qe1 += __shfl_xor(qe1, d);
    se2 += __shfl_xor(se2, d); qe2 += __shfl_xor(qe2, d);
    se3 += __shfl_xor(se3, d); qe3 += __shfl_xor(qe3, d);
  }
  float val = 0.f;
  if (lane < 4)
    val = 0.5f * ((se0 * se0 - qe0) + (se1 * se1 - qe1) +
                  (se2 * se2 - qe2) + (se3 * se3 - qe3));
  if (lane < Ff)
    val += emb1[(long)lane * (Vv + 1) + sidx[w][lane]] * sxv[w][lane];
  #pragma unroll
  for (int d = 1; d < 64; d <<= 1) val += __shfl_xor(val, d);
  if (lane == 0) p[n] = val + bias[0];
}

// ---------------- bf16 MFMA GEMM: C(16384 x 400) = A(16384 x K) @ Wt^T + bias ----------------
// Wt PRE-TRANSPOSED [n][k], K padded to mult of 64 (zero pads). Block tile 128M x 80N, BK=64,
// 4 waves, wave tile 32M x 80N. Staging via global_load_lds width-16 into LINEAR LDS with
// XOR-swizzle (kc ^= row&7) applied to BOTH the global source chunk and the ds_read slot
// (rule 21: both-sides involution) -> 2-way (free) bank conflicts on fragment reads.
// XCD-aware bijective swizzle of the 640-block grid: each XCD gets contiguous m-range x all
// 5 n-tiles -> A panel reused 5x from in-XCD L2, Wt (<=0.5MB) resident per-XCD.
// Fused epilogue: bf16 store + LDS-combined (4 waves) per-column sum/sumsq atomics.
__global__ __launch_bounds__(256) void gemm_bf16(
    const __hip_bfloat16* __restrict__ A, const __hip_bfloat16* __restrict__ Wt,
    const float* __restrict__ bias, __hip_bfloat16* __restrict__ C,
    float* __restrict__ s, float* __restrict__ ss, const int K, const int ldc) {
  __shared__ __align__(16) short As_s[128 * 64];
  __shared__ __align__(16) short Bs_s[80 * 64];
  __shared__ float redS[4][5][16], redQ[4][5][16];
  const int tid = threadIdx.x;
  const int lin = blockIdx.x + blockIdx.y * 5;          // 0..639, 640%8==0 -> bijective
  const int v   = (lin & 7) * 80 + (lin >> 3);          // XCD c -> contiguous chunk c*80..
  const int n0  = (v % 5) * 80;
  const int m0  = (v / 5) * 128;
  const int w = tid >> 6, lane = tid & 63;
  const int lm = lane & 15, qd = lane >> 4;

  floatx4 acc[2][5];
  #pragma unroll
  for (int i = 0; i < 2; ++i)
    #pragma unroll
    for (int j = 0; j < 5; ++j)
      acc[i][j] = (floatx4){0.f, 0.f, 0.f, 0.f};

  const int nk = K >> 6;
  for (int ks = 0; ks < nk; ++ks) {
    const int k0 = ks << 6;
    // stage A: 1024 16B-chunks, chunk c=(m,kc): LDS slot c holds global chunk (m, kc^(m&7))
    #pragma unroll
    for (int j = 0; j < 4; ++j) {
      const int c = tid + j * 256;
      const int m = c >> 3, kc = c & 7;
      gload16(&As_s[c * 8], &A[(size_t)(m0 + m) * K + k0 + ((kc ^ (m & 7)) << 3)]);
    }
    // stage B: 640 16B-chunks (last pass: waves 0,1 only -> full-exec waves)
    #pragma unroll
    for (int j = 0; j < 3; ++j) {
      const int c = tid + j * 256;
      if (c < 640) {
        const int nn = c >> 3, kc = c & 7;
        gload16(&Bs_s[c * 8], &Wt[(size_t)(n0 + nn) * K + k0 + ((kc ^ (nn & 7)) << 3)]);
      }
    }
    __syncthreads();
    #pragma unroll
    for (int h = 0; h < 2; ++h) {
      const int sl = (h * 32 + qd * 8) >> 3;   // 16B slot index within row
      const int r0 = w * 32 + lm, r1 = r0 + 16;
      const short8 a0 = *(const short8*)&As_s[r0 * 64 + ((sl ^ (r0 & 7)) << 3)];
      const short8 a1 = *(const short8*)&As_s[r1 * 64 + ((sl ^ (r1 & 7)) << 3)];
      #pragma unroll
      for (int nt = 0; nt < 5; ++nt) {
        const int rn = nt * 16 + lm;
        const short8 bfr = *(const short8*)&Bs_s[rn * 64 + ((sl ^ (rn & 7)) << 3)];
        acc[0][nt] = __builtin_amdgcn_mfma_f32_16x16x32_bf16(a0, bfr, acc[0][nt], 0, 0, 0);
        acc[1][nt] = __builtin_amdgcn_mfma_f32_16x16x32_bf16(a1, bfr, acc[1][nt], 0, 0, 0);
      }
    }
    __syncthreads();
  }

  // epilogue: C/D layout col=lane&15, row=qd*4+reg
  const int rb = m0 + w * 32 + qd * 4;
  #pragma unroll
  for (int nt = 0; nt < 5; ++nt) {
    const int col = n0 + nt * 16 + lm;
    const float bc = bias[col];
    float cs = 0.f, cq = 0.f;
    #pragma unroll
    for (int mt = 0; mt < 2; ++mt) {
      #pragma unroll
      for (int r = 0; r < 4; ++r) {
        const float vv = acc[mt][nt][r] + bc;
        const __hip_bfloat16 hv = __float2bfloat16(vv);
        C[(size_t)(rb + mt * 16 + r) * ldc + col] = hv;
        const float vf = __bfloat162float(hv);
        cs += vf; cq += vf * vf;
      }
    }
    cs += __shfl_xor(cs, 16); cq += __shfl_xor(cq, 16);
    cs += __shfl_xor(cs, 32); cq += __shfl_xor(cq, 32);
    if (lane < 16) { redS[w][nt][lm] = cs; redQ[w][nt][lm] = cq; }
  }
  __syncthreads();
  if (tid < 80) {  // combine the 4 waves -> one atomic pair per column per block
    const int nt = tid >> 4, l = tid & 15;
    const int col = n0 + nt * 16 + l;
    atomicAdd(&s[col],  redS[0][nt][l] + redS[1][nt][l] + redS[2][nt][l] + redS[3][nt][l]);
    atomicAdd(&ss[col], redQ[0][nt][l] + redQ[1][nt][l] + redQ[2][nt][l] + redQ[3][nt][l]);
  }
}

// ---------------- prep2 (BN1 coefficients inline): W2t[n][k] = a1[k]*W2[k][n] (pad->448); b2p[n] = b2[n] + sum_k c1[k]*W2[k][n] ----------------
__global__ __launch_bounds__(256) void prep2_kernel(
    const float* __restrict__ W2,
    const float* __restrict__ s1, const float* __restrict__ ss1,
    const float* __restrict__ g1, const float* __restrict__ be1,
    const float* __restrict__ b2, __hip_bfloat16* __restrict__ W2t, float* __restrict__ b2p) {
  __shared__ float sa1[Hh], sc1[Hh];
  __shared__ float red[256];
  const int n = blockIdx.x, t = threadIdx.x;
  for (int k = t; k < Hh; k += 256) {
    const float mu = s1[k] * (1.f / Nn);
    const float var = ss1[k] * (1.f / Nn) - mu * mu;
    const float a = g1[k] * rsqrtf(var + EPSf);
    sa1[k] = a;
    sc1[k] = be1[k] - a * mu;
  }
  __syncthreads();
  float acc = 0.f;
  for (int k = t; k < KP2; k += 256) {
    if (k < Hh) {
      const float wv = W2[(size_t)k * Hh + n];
      W2t[(size_t)n * KP2 + k] = __float2bfloat16(sa1[k] * wv);
      acc += sc1[k] * wv;
    } else {
      W2t[(size_t)n * KP2 + k] = __float2bfloat16(0.f);
    }
  }
  red[t] = acc; __syncthreads();
  for (int d = 128; d > 0; d >>= 1) { if (t < d) red[t] += red[t + d]; __syncthreads(); }
  if (t == 0) b2p[n] = b2[n] + red[0];
}

// ---------------- final (BN2 alpha/c2 inline): out[n] = p[n] + dot(alpha, x2[n,:]) + c2 ----------------
__global__ __launch_bounds__(256) void final_kernel(
    const __hip_bfloat16* __restrict__ x2,
    const float* __restrict__ s2, const float* __restrict__ ss2,
    const float* __restrict__ g2, const float* __restrict__ be2,
    const float* __restrict__ p, float* __restrict__ out) {
  __shared__ float sal[Hh];
  __shared__ float red[256];
  const int t = threadIdx.x;
  float part = 0.f;
  for (int h = t; h < Hh; h += 256) {
    const float mu = s2[h] * (1.f / Nn);
    const float var = ss2[h] * (1.f / Nn) - mu * mu;
    const float al = g2[h] * rsqrtf(var + EPSf);
    sal[h] = al;
    part += be2[h] - al * mu;
  }
  red[t] = part; __syncthreads();
  for (int d = 128; d > 0; d >>= 1) { if (t < d) red[t] += red[t + d]; __syncthreads(); }
  __syncthreads();
  const float c2 = red[0];

  const int w = t >> 6, lane = t & 63;
  const int n = blockIdx.x * 4 + w;
  const unsigned short* row = (const unsigned short*)(x2 + (size_t)n * Hh);
  float acc = 0.f;
  for (int h0 = lane * 4; h0 < Hh; h0 += 256) {
    const ushort4 u = *(const ushort4*)&row[h0];
    acc += bf2f(u.x) * sal[h0] + bf2f(u.y) * sal[h0 + 1]
         + bf2f(u.z) * sal[h0 + 2] + bf2f(u.w) * sal[h0 + 3];
  }
  #pragma unroll
  for (int d = 1; d < 64; d <<= 1) acc += __shfl_xor(acc, d);
  if (lane == 0) out[n] = p[n] + acc + c2;
}

extern "C" void kernel_launch(void* const* d_in, const int* in_sizes, int n_in,
                              void* d_out, int out_size, void* d_ws, size_t ws_size,
                              hipStream_t stream) {
  const int*   xi   = (const int*)d_in[0];
  const float* xv   = (const float*)d_in[1];
  const float* emb1 = (const float*)d_in[2];
  const float* emb2 = (const float*)d_in[3];
  const float* W1   = (const float*)d_in[4];
  const float* b1   = (const float*)d_in[5];
  const float* g1   = (const float*)d_in[6];
  const float* be1  = (const float*)d_in[7];
  const float* W2   = (const float*)d_in[8];
  const float* b2   = (const float*)d_in[9];
  const float* g2   = (const float*)d_in[10];
  const float* be2  = (const float*)d_in[11];
  const float* bias = (const float*)d_in[12];
  float* out = (float*)d_out;

  char* ws = (char*)d_ws;
  __hip_bfloat16* deep = (__hip_bfloat16*)ws;  ws += (size_t)Nn * KP1 * 2;
  __hip_bfloat16* x1b  = (__hip_bfloat16*)ws;  ws += (size_t)Nn * KP2 * 2;
  __hip_bfloat16* x2b  = (__hip_bfloat16*)ws;  ws += (size_t)Nn * Hh * 2;
  __hip_bfloat16* W1t  = (__hip_bfloat16*)ws;  ws += (size_t)Hh * KP1 * 2;
  __hip_bfloat16* W2t  = (__hip_bfloat16*)ws;  ws += (size_t)Hh * KP2 * 2;
  float* p    = (float*)ws;  ws += (size_t)Nn * 4;
  float* s1   = (float*)ws;  ws += Hh * 4;   // s1,ss1,s2,ss2 contiguous (zeroed by embed launch)
  float* ss1  = (float*)ws;  ws += Hh * 4;
  float* s2   = (float*)ws;  ws += Hh * 4;
  float* ss2  = (float*)ws;  ws += Hh * 4;
  float* b2p  = (float*)ws;  ws += Hh * 4;

  embed_kernel<<<4497, 256, 0, stream>>>(xi, xv, emb1, emb2, bias, W1, deep, p, W1t, s1, x1b);
  gemm_bf16<<<dim3(5, Nn / 128), 256, 0, stream>>>(deep, W1t, b1, x1b, s1, ss1, KP1, KP2);
  prep2_kernel<<<Hh, 256, 0, stream>>>(W2, s1, ss1, g1, be1, b2, W2t, b2p);
  gemm_bf16<<<dim3(5, Nn / 128), 256, 0, stream>>>(x1b, W2t, b2p, x2b, s2, ss2, KP2, Hh);
  final_kernel<<<Nn / 4, 256, 0, stream>>>(x2b, s2, ss2, g2, be2, p, out);
}